// Round 4
// baseline (504.946 us; speedup 1.0000x reference)
//
#include <hip/hip_runtime.h>

#define T_LEN 1024
#define NBATCH 256
#define HDIM 12
#define PG_STRIDE 12288  // 256*48 halves per timestep
#define X3_TB 16         // padded halves per (t,b)

typedef __fp16 fp16x2 __attribute__((ext_vector_type(2)));

// ---------- helpers ----------
#if __has_builtin(__builtin_amdgcn_exp2f)
#define EXP2F(x) __builtin_amdgcn_exp2f(x)
#else
#define EXP2F(x) exp2f(x)
#endif
#if __has_builtin(__builtin_amdgcn_rcpf)
#define RCPF(x) __builtin_amdgcn_rcpf(x)
#else
#define RCPF(x) (1.0f / (x))
#endif

__device__ __forceinline__ unsigned rlu(unsigned v, int lane) {
#if __has_builtin(__builtin_amdgcn_readlane)
  return (unsigned)__builtin_amdgcn_readlane((int)v, lane);
#else
  return (unsigned)__shfl((int)v, lane, 64);
#endif
}

template <int Q>
__device__ __forceinline__ float qb(float v) {
#if __has_builtin(__builtin_amdgcn_mov_dpp)
  return __int_as_float(__builtin_amdgcn_mov_dpp(__float_as_int(v), Q * 0x55, 0xF, 0xF, true));
#else
  return __shfl(v, (threadIdx.x & ~3) | Q, 64);
#endif
}

// lane i <- lane i-4 within 16-lane row (data moves to higher lanes)
__device__ __forceinline__ float row_shr4(float v) {
#if __has_builtin(__builtin_amdgcn_mov_dpp)
  return __int_as_float(__builtin_amdgcn_mov_dpp(__float_as_int(v), 0x114, 0xF, 0xF, true));
#else
  return __shfl(v, (threadIdx.x & 63) - 4, 64);
#endif
}

__device__ __forceinline__ float nl_gate(float x, float kq, float c1, float c0) {
  float e = EXP2F(kq * x);
  float r = RCPF(1.0f + e);
  return fmaf(c1, r, c0);
}
__device__ __forceinline__ float tanh_fast(float x) {
  float e = EXP2F(-2.8853900817779268f * x);
  float r = RCPF(1.0f + e);
  return fmaf(2.0f, r, -1.0f);
}

__device__ __forceinline__ float h16tof(unsigned short u) {
  union { unsigned short s; _Float16 h; } c; c.s = u; return (float)c.h;
}
__device__ __forceinline__ unsigned short f16bits(float f) {
  union { unsigned short s; _Float16 h; } c; c.h = (_Float16)f; return c.s;
}
__device__ __forceinline__ float h16lo(unsigned u) {
  union { unsigned short s; _Float16 h; } c; c.s = (unsigned short)(u & 0xffffu); return (float)c.h;
}
__device__ __forceinline__ float h16hi(unsigned u) {
  union { unsigned short s; _Float16 h; } c; c.s = (unsigned short)(u >> 16); return (float)c.h;
}
__device__ __forceinline__ unsigned pk16(float a, float b) {
#if __has_builtin(__builtin_amdgcn_cvt_pkrtz)
  fp16x2 h = __builtin_amdgcn_cvt_pkrtz(a, b);
  return __builtin_bit_cast(unsigned, h);
#else
  return (unsigned)f16bits(a) | ((unsigned)f16bits(b) << 16);
#endif
}
__device__ __forceinline__ unsigned plo(unsigned a, unsigned b) { return (a & 0xffffu) | (b << 16); }
__device__ __forceinline__ unsigned phi(unsigned a, unsigned b) { return (a >> 16) | (b & 0xffff0000u); }

__device__ __forceinline__ float dot2acc(unsigned a, unsigned b, float c) {
#if __has_builtin(__builtin_amdgcn_fdot2)
  return __builtin_amdgcn_fdot2(__builtin_bit_cast(fp16x2, a), __builtin_bit_cast(fp16x2, b), c, false);
#else
  return fmaf(h16lo(a), h16lo(b), fmaf(h16hi(a), h16hi(b), c));
#endif
}

// gate nonlinearity + c/h update (i,f,g,o quad-broadcast via DPP)
__device__ __forceinline__ float nlup(float av, float& cv, float kq, float c1, float c0) {
  float n = nl_gate(av, kq, c1, c0);
  float si = qb<0>(n), sf = qb<1>(n), tg = qb<2>(n), so = qb<3>(n);
  cv = fmaf(sf, cv, si * tg);
  return so * tanh_fast(cv);
}
// pack h pairs (f16x2) via row_shr4 + pkrtz; broadcast 6 pairs via readlane
__device__ __forceinline__ unsigned packb(float hq, unsigned* hown) {
  float sh = row_shr4(hq);
  unsigned pkv = pk16(sh, hq);
  hown[0] = rlu(pkv, 4);  hown[1] = rlu(pkv, 12); hown[2] = rlu(pkv, 20);
  hown[3] = rlu(pkv, 28); hown[4] = rlu(pkv, 36); hown[5] = rlu(pkv, 44);
  return pkv;
}

// ============================================================================
// Kernel 0: pregate  pg[t][b][lane48] = f16( bih0+bhh0 + Wih0 . x[b][t] )
// ============================================================================
__global__ __launch_bounds__(64, 4) void pregate_kernel(
    const float* __restrict__ mfcc, const float* __restrict__ Wih,
    const float* __restrict__ bih, const float* __restrict__ bhh,
    unsigned short* __restrict__ pg) {
  const int b = blockIdx.x & 255;
  const int tc = blockIdx.x >> 8;  // 0..7, chunks of 128 t
  const int lane = threadIdx.x;
  const int j = lane >> 2, q = lane & 3;
  const int jj = (j < HDIM) ? j : (HDIM - 1);
  const int g = q * HDIM + jj;
  float w[HDIM];
#pragma unroll
  for (int m = 0; m < HDIM; ++m) w[m] = Wih[g * HDIM + m];
  const float bias = bih[g] + bhh[g];
  const bool wr = (lane < 48);
  const float* xb = mfcc + (b * T_LEN + tc * 128) * HDIM;
  unsigned short* out = pg + (unsigned)(tc * 128 * NBATCH + b) * 48 + lane;
#pragma unroll 2
  for (int t = 0; t < 128; ++t) {
    float acc = bias;
#pragma unroll
    for (int d = 0; d < HDIM; ++d) acc = fmaf(w[d], xb[d], acc);
    if (wr) *out = f16bits(acc);
    xb += HDIM;
    out += PG_STRIDE;
  }
}

// ============================================================================
// Kernel 1: 3-layer LSTM. One block (3 waves) per batch element; wave l owns
// layer l, staggered by 1 step; h exchanged via 192B LDS mailbox (f16x2 pairs),
// double-buffered, 1 barrier per superstep. Own-h recurrence via readlane.
// LDS dword map: h0buf0@0, h0buf1@8, h1buf0@16, h1buf1@24, dump@32..39
// (each buf: 6 pair-dwords + 2 pad dwords).
// ============================================================================
__global__ __launch_bounds__(192, 1) void lstm3_kernel(
    const unsigned short* __restrict__ pg,
    const float* __restrict__ Wih, const float* __restrict__ Whh,
    const float* __restrict__ bih, const float* __restrict__ bhh,
    unsigned short* __restrict__ x3) {
  __shared__ __align__(16) unsigned ldsb[40];
  const int b = blockIdx.x;
  const int tid = threadIdx.x;
  const int wid = tid >> 6;
  const int lane = tid & 63;
  const int j = lane >> 2, q = lane & 3;
  const int jj = (j < HDIM) ? j : (HDIM - 1);
  const int g = q * HDIM + jj;
  const int row = (wid * 48 + g) * HDIM;

  unsigned wih_pk[6], whh_pk[6];
#pragma unroll
  for (int m = 0; m < 6; ++m) {
    wih_pk[m] = pk16(Wih[row + 2 * m], Wih[row + 2 * m + 1]);
    whh_pk[m] = pk16(Whh[row + 2 * m], Whh[row + 2 * m + 1]);
  }
  const float bias = bih[wid * 48 + g] + bhh[wid * 48 + g];  // wave0: folded in pregate
  const float kq = (q == 2) ? -2.8853900817779268f : -1.4426950408889634f;
  const float c1c = (q == 2) ? 2.0f : 1.0f;
  const float c0c = (q == 2) ? -1.0f : 0.0f;

  float cv = 0.f;
  unsigned hown[6] = {0u, 0u, 0u, 0u, 0u, 0u};

  // per-lane static LDS write addresses (valid pairs from upper half of each
  // 8-lane group; lower halves + overflow groups go to dump/padding)
  const int grpi = lane >> 3;
  const bool upper = (lane & 7) >= 4;
  const int wb = (wid == 0) ? 0 : 16;
  const int wr0 = upper ? (wb + grpi) : (32 + grpi);
  const int wr1 = upper ? (wb + 8 + grpi) : (32 + grpi);

  // pregate stream (wave 0 only), prefetched 2 supersteps deep
  const unsigned short* pgl = pg + (unsigned)b * 48 + lane;
  unsigned short pgc0 = pgl[0];
  unsigned short pgc1 = pgl[PG_STRIDE];
  const unsigned short* pgp0 = pgl + 2 * PG_STRIDE;
  const unsigned short* pgp1 = pgl + 3 * PG_STRIDE;

  unsigned short* x3w = x3 + b * X3_TB + (lane >> 2);  // wave 2 output

  auto w0body = [&](int P) {
    float pgf = h16tof(P == 0 ? pgc0 : pgc1);
    if (P == 0) { pgc0 = *pgp0; pgp0 += 2 * PG_STRIDE; }
    else        { pgc1 = *pgp1; pgp1 += 2 * PG_STRIDE; }
    float aE = dot2acc(whh_pk[0], hown[0], pgf);
    aE = dot2acc(whh_pk[1], hown[1], aE);
    aE = dot2acc(whh_pk[2], hown[2], aE);
    float aO = dot2acc(whh_pk[3], hown[3], 0.f);
    aO = dot2acc(whh_pk[4], hown[4], aO);
    aO = dot2acc(whh_pk[5], hown[5], aO);
    float hq = nlup(aE + aO, cv, kq, c1c, c0c);
    unsigned pkv = packb(hq, hown);
    ldsb[P == 0 ? wr0 : wr1] = pkv;
  };

  auto w12body = [&](int P, bool isw2) {
    const int off = isw2 ? (P == 0 ? 24 : 16) : (P == 0 ? 8 : 0);
    uint4 hA = *(const uint4*)(ldsb + off);      // input-h pairs 0..3
    uint2 hB = *(const uint2*)(ldsb + off + 4);  // pairs 4..5
    float aO = dot2acc(whh_pk[0], hown[0], bias);
    aO = dot2acc(whh_pk[1], hown[1], aO);
    aO = dot2acc(whh_pk[2], hown[2], aO);
    aO = dot2acc(whh_pk[3], hown[3], aO);
    aO = dot2acc(whh_pk[4], hown[4], aO);
    aO = dot2acc(whh_pk[5], hown[5], aO);
    float aI = dot2acc(wih_pk[0], hA.x, 0.f);
    aI = dot2acc(wih_pk[1], hA.y, aI);
    aI = dot2acc(wih_pk[2], hA.z, aI);
    aI = dot2acc(wih_pk[3], hA.w, aI);
    aI = dot2acc(wih_pk[4], hB.x, aI);
    aI = dot2acc(wih_pk[5], hB.y, aI);
    float hq = nlup(aO + aI, cv, kq, c1c, c0c);
    unsigned pkv = packb(hq, hown);
    if (!isw2) {
      ldsb[P == 0 ? wr0 : wr1] = pkv;
    } else {
      *x3w = f16bits(hq);        // quad-mates write same addr, same value
      x3w += NBATCH * X3_TB;
      (void)pkv;
    }
  };

  // s = 0
  __syncthreads();
  if (wid == 0) w0body(0);
  // s = 1
  __syncthreads();
  if (wid == 0) w0body(1);
  else if (wid == 1) w12body(1, false);
  // s = 2 .. 1023 (branch-free interior, parity static via unroll)
  for (int it = 0; it < 511; ++it) {
    __syncthreads();
    if (wid == 0) w0body(0);
    else if (wid == 1) w12body(0, false);
    else w12body(0, true);
    __syncthreads();
    if (wid == 0) w0body(1);
    else if (wid == 1) w12body(1, false);
    else w12body(1, true);
  }
  // s = 1024
  __syncthreads();
  if (wid == 1) w12body(0, false);
  else if (wid == 2) w12body(0, true);
  // s = 1025
  __syncthreads();
  if (wid == 2) w12body(1, true);
}

// ============================================================================
// Kernel 2: per-timestep MLP + batch BN + lambda projection. 1 block / t.
// f16 staging, v_dot2_f32_f16 fc2 inner loop (k-paired).
// ============================================================================
__global__ __launch_bounds__(256, 2) void mlp_out_kernel(
    const unsigned short* __restrict__ x3, const float* __restrict__ mfcc,
    const float* __restrict__ w1, const float* __restrict__ g1,
    const float* __restrict__ be1, const float* __restrict__ w2,
    const float* __restrict__ g2, const float* __restrict__ be2,
    const float* __restrict__ w3, const float* __restrict__ b3,
    const float* __restrict__ WI, float* __restrict__ outp) {
  __shared__ __align__(16) unsigned char smem[55296];
  unsigned short* h1 = (unsigned short*)smem;        // [64][256] f16
  unsigned* w2p = (unsigned*)(smem + 32768);         // [32][128] k-paired f16x2
  float* p3 = (float*)smem;                          // [8][256][6] (alias, 48KB)
  float* w3s = (float*)(smem + 49152);               // [6][128]
  float* stp = (float*)(smem + 52224);               // stat partials
  float* scsh = (float*)(smem + 54272);              // [128][2]

  const int t = blockIdx.x;
  const int tid = threadIdx.x;

  // ---- phase 1: stage w2 k-paired + w3 ----
  for (int i = tid; i < 4096; i += 256) {
    int kp = i >> 7, c = i & 127;
    w2p[kp * 128 + c] = pk16(w2[c * 64 + 2 * kp], w2[c * 64 + 2 * kp + 1]);
  }
  for (int i = tid; i < 768; i += 256) w3s[i] = w3[i];

  // ---- phase 2: fc1 (bias cancels under BN); thread = one b ----
  {
    const unsigned short* xp = x3 + t * (NBATCH * X3_TB) + tid * X3_TB;
    uint2 u0 = ((const uint2*)xp)[0];
    uint2 u1 = ((const uint2*)xp)[1];
    uint2 u2 = ((const uint2*)xp)[2];
    const float x[HDIM] = {h16lo(u0.x), h16hi(u0.x), h16lo(u0.y), h16hi(u0.y),
                           h16lo(u1.x), h16hi(u1.x), h16lo(u1.y), h16hi(u1.y),
                           h16lo(u2.x), h16hi(u2.x), h16lo(u2.y), h16hi(u2.y)};
#pragma unroll 8
    for (int ch = 0; ch < 64; ++ch) {
      float a = 0.f;
#pragma unroll
      for (int d = 0; d < HDIM; ++d) a = fmaf(w1[ch * HDIM + d], x[d], a);
      h1[ch * 256 + tid] = f16bits(a);
    }
  }
  __syncthreads();

  // ---- phase 3: BN1 stats over b (on stored f16 values) ----
  {
    const int ch = tid & 63, grp = tid >> 6;
    const uint4* rp = (const uint4*)(h1 + ch * 256 + grp * 64);
    float s = 0.f, sq = 0.f;
#pragma unroll
    for (int i = 0; i < 8; ++i) {
      uint4 v = rp[(i + ch) & 7];
      float f0 = h16lo(v.x), f1 = h16hi(v.x), f2 = h16lo(v.y), f3 = h16hi(v.y);
      float f4 = h16lo(v.z), f5 = h16hi(v.z), f6 = h16lo(v.w), f7 = h16hi(v.w);
      s += ((f0 + f1) + (f2 + f3)) + ((f4 + f5) + (f6 + f7));
      sq = fmaf(f0, f0, sq); sq = fmaf(f1, f1, sq);
      sq = fmaf(f2, f2, sq); sq = fmaf(f3, f3, sq);
      sq = fmaf(f4, f4, sq); sq = fmaf(f5, f5, sq);
      sq = fmaf(f6, f6, sq); sq = fmaf(f7, f7, sq);
    }
    stp[(ch * 4 + grp) * 2] = s;
    stp[(ch * 4 + grp) * 2 + 1] = sq;
  }
  __syncthreads();
  if (tid < 64) {
    float s = 0.f, sq = 0.f;
#pragma unroll
    for (int gg = 0; gg < 4; ++gg) {
      s += stp[(tid * 4 + gg) * 2];
      sq += stp[(tid * 4 + gg) * 2 + 1];
    }
    float mu = s * (1.f / 256.f);
    float var = fmaf(-mu, mu, sq * (1.f / 256.f));
    float sc = g1[tid] * rsqrtf(var + 1e-5f);
    scsh[tid * 2] = sc;
    scsh[tid * 2 + 1] = fmaf(-sc, mu, be1[tid]);
  }
  __syncthreads();
  // ---- phase 3c: apply BN1 + relu in place ----
  {
    const int ch = tid & 63, grp = tid >> 6;
    const float sc = scsh[ch * 2], sh = scsh[ch * 2 + 1];
    uint4* rp = (uint4*)(h1 + ch * 256 + grp * 64);
#pragma unroll
    for (int i = 0; i < 8; ++i) {
      uint4 v = rp[(i + ch) & 7];
      float f0 = fmaxf(fmaf(sc, h16lo(v.x), sh), 0.f);
      float f1 = fmaxf(fmaf(sc, h16hi(v.x), sh), 0.f);
      float f2 = fmaxf(fmaf(sc, h16lo(v.y), sh), 0.f);
      float f3 = fmaxf(fmaf(sc, h16hi(v.y), sh), 0.f);
      float f4 = fmaxf(fmaf(sc, h16lo(v.z), sh), 0.f);
      float f5 = fmaxf(fmaf(sc, h16hi(v.z), sh), 0.f);
      float f6 = fmaxf(fmaf(sc, h16lo(v.w), sh), 0.f);
      float f7 = fmaxf(fmaf(sc, h16hi(v.w), sh), 0.f);
      v.x = pk16(f0, f1); v.y = pk16(f2, f3);
      v.z = pk16(f4, f5); v.w = pk16(f6, f7);
      rp[(i + ch) & 7] = v;
    }
  }
  __syncthreads();

  // ---- phase 4: fc2, 8b x 16c per thread, dot2 over k-pairs ----
  const int tb = tid & 31, tc = tid >> 5;
  const int b0 = tb * 8, cc0 = tc * 16;
  float acc[8][16];
#pragma unroll
  for (int bi = 0; bi < 8; ++bi)
#pragma unroll
    for (int ci = 0; ci < 16; ++ci) acc[bi][ci] = 0.f;

  for (int kp = 0; kp < 32; ++kp) {
    uint4 aL = *(const uint4*)(h1 + (2 * kp) * 256 + b0);
    uint4 aH = *(const uint4*)(h1 + (2 * kp + 1) * 256 + b0);
    const unsigned* wrow = w2p + kp * 128 + cc0;
    uint4 wA = ((const uint4*)wrow)[0];
    uint4 wB = ((const uint4*)wrow)[1];
    uint4 wC = ((const uint4*)wrow)[2];
    uint4 wD = ((const uint4*)wrow)[3];
    unsigned ap[8];
    ap[0] = plo(aL.x, aH.x); ap[1] = phi(aL.x, aH.x);
    ap[2] = plo(aL.y, aH.y); ap[3] = phi(aL.y, aH.y);
    ap[4] = plo(aL.z, aH.z); ap[5] = phi(aL.z, aH.z);
    ap[6] = plo(aL.w, aH.w); ap[7] = phi(aL.w, aH.w);
    const unsigned wp[16] = {wA.x, wA.y, wA.z, wA.w, wB.x, wB.y, wB.z, wB.w,
                             wC.x, wC.y, wC.z, wC.w, wD.x, wD.y, wD.z, wD.w};
#pragma unroll
    for (int bi = 0; bi < 8; ++bi)
#pragma unroll
      for (int ci = 0; ci < 16; ++ci) acc[bi][ci] = dot2acc(ap[bi], wp[ci], acc[bi][ci]);
  }

  // ---- phase 5: BN2 stats (shuffle-reduce over tb) ----
  {
    float sv[16], qv[16];
#pragma unroll
    for (int ci = 0; ci < 16; ++ci) {
      float s = 0.f, sq = 0.f;
#pragma unroll
      for (int bi = 0; bi < 8; ++bi) {
        s += acc[bi][ci];
        sq = fmaf(acc[bi][ci], acc[bi][ci], sq);
      }
      sv[ci] = s; qv[ci] = sq;
    }
#pragma unroll
    for (int m = 1; m <= 16; m <<= 1) {
#pragma unroll
      for (int ci = 0; ci < 16; ++ci) {
        sv[ci] += __shfl_xor(sv[ci], m, 64);
        qv[ci] += __shfl_xor(qv[ci], m, 64);
      }
    }
    if (tb == 0) {
#pragma unroll
      for (int ci = 0; ci < 16; ++ci) {
        stp[(cc0 + ci) * 2] = sv[ci];
        stp[(cc0 + ci) * 2 + 1] = qv[ci];
      }
    }
  }
  __syncthreads();
  if (tid < 128) {
    float mu = stp[tid * 2] * (1.f / 256.f);
    float var = fmaf(-mu, mu, stp[tid * 2 + 1] * (1.f / 256.f));
    float sc = g2[tid] * rsqrtf(var + 1e-5f);
    scsh[tid * 2] = sc;
    scsh[tid * 2 + 1] = fmaf(-sc, mu, be2[tid]);
  }
  __syncthreads();
#pragma unroll
  for (int ci = 0; ci < 16; ++ci) {
    const float sc = scsh[(cc0 + ci) * 2], sh = scsh[(cc0 + ci) * 2 + 1];
#pragma unroll
    for (int bi = 0; bi < 8; ++bi)
      acc[bi][ci] = fmaxf(fmaf(sc, acc[bi][ci], sh), 0.f);
  }

  // ---- phase 6: fc3 partials over this thread's 16 channels ----
  {
    float lam[8][6];
#pragma unroll
    for (int bi = 0; bi < 8; ++bi)
#pragma unroll
      for (int k6 = 0; k6 < 6; ++k6) lam[bi][k6] = 0.f;
#pragma unroll
    for (int ci = 0; ci < 16; ++ci) {
      float wv[6];
#pragma unroll
      for (int k6 = 0; k6 < 6; ++k6) wv[k6] = w3s[k6 * 128 + cc0 + ci];
#pragma unroll
      for (int bi = 0; bi < 8; ++bi)
#pragma unroll
        for (int k6 = 0; k6 < 6; ++k6)
          lam[bi][k6] = fmaf(acc[bi][ci], wv[k6], lam[bi][k6]);
    }
#pragma unroll
    for (int bi = 0; bi < 8; ++bi)
#pragma unroll
      for (int k6 = 0; k6 < 6; ++k6)
        p3[(tc * 256 + b0 + bi) * 6 + k6] = lam[bi][k6];
  }
  __syncthreads();

  // ---- phase 7: reduce lambda, apply projection, write out ----
  {
    float lm[6];
#pragma unroll
    for (int k6 = 0; k6 < 6; ++k6) lm[k6] = b3[k6];
#pragma unroll
    for (int tcc = 0; tcc < 8; ++tcc)
#pragma unroll
      for (int k6 = 0; k6 < 6; ++k6) lm[k6] += p3[(tcc * 256 + tid) * 6 + k6];

    const float4* mp = (const float4*)(mfcc + (tid * T_LEN + t) * HDIM);
    float4 m0 = mp[0], m1 = mp[1], m2 = mp[2];
    const float x[HDIM] = {m0.x, m0.y, m0.z, m0.w, m1.x, m1.y,
                           m1.z, m1.w, m2.x, m2.y, m2.z, m2.w};
    float o[HDIM];
#pragma unroll
    for (int e = 0; e < HDIM; ++e) o[e] = x[e];
#pragma unroll
    for (int k6 = 0; k6 < 6; ++k6) {
      float pk[HDIM];
#pragma unroll
      for (int e = 0; e < HDIM; ++e) pk[e] = 0.f;
#pragma unroll
      for (int d = 0; d < HDIM; ++d)
#pragma unroll
        for (int e = 0; e < HDIM; ++e)
          pk[e] = fmaf(x[d], WI[(k6 * HDIM + d) * HDIM + e], pk[e]);
#pragma unroll
      for (int e = 0; e < HDIM; ++e) o[e] = fmaf(lm[k6], pk[e], o[e]);
    }
    float4* op4 = (float4*)(outp + (tid * T_LEN + t) * HDIM);
    op4[0] = make_float4(o[0], o[1], o[2], o[3]);
    op4[1] = make_float4(o[4], o[5], o[6], o[7]);
    op4[2] = make_float4(o[8], o[9], o[10], o[11]);
  }
}

// ============================================================================
extern "C" void kernel_launch(void* const* d_in, const int* in_sizes, int n_in,
                              void* d_out, int out_size, void* d_ws, size_t ws_size,
                              hipStream_t stream) {
  const float* mfcc = (const float*)d_in[0];
  const float* Wih = (const float*)d_in[1];
  const float* Whh = (const float*)d_in[2];
  const float* bih = (const float*)d_in[3];
  const float* bhh = (const float*)d_in[4];
  const float* w1 = (const float*)d_in[5];
  const float* g1 = (const float*)d_in[7];
  const float* be1 = (const float*)d_in[8];
  const float* w2 = (const float*)d_in[9];
  const float* g2 = (const float*)d_in[11];
  const float* be2 = (const float*)d_in[12];
  const float* w3 = (const float*)d_in[13];
  const float* b3 = (const float*)d_in[14];
  const float* WI = (const float*)d_in[15];

  // ws: pregate f16 [1024][256][48] = 25,165,824 B ; x3 f16 [1024][256][16] = 8,388,608 B
  unsigned short* pg = (unsigned short*)d_ws;
  unsigned short* x3 = (unsigned short*)((char*)d_ws + 25165824);
  float* out = (float*)d_out;

  hipLaunchKernelGGL(pregate_kernel, dim3(2048), dim3(64), 0, stream,
                     mfcc, Wih, bih, bhh, pg);
  hipLaunchKernelGGL(lstm3_kernel, dim3(NBATCH), dim3(192), 0, stream,
                     pg, Wih, Whh, bih, bhh, x3);
  hipLaunchKernelGGL(mlp_out_kernel, dim3(T_LEN), dim3(256), 0, stream,
                     x3, mfcc, w1, g1, be1, w2, g2, be2, w3, b3, WI, out);
}

// Round 5
// 442.679 us; speedup vs baseline: 1.1407x; 1.1407x over previous
//
#include <hip/hip_runtime.h>

#define T_LEN 1024
#define NBATCH 256
#define HDIM 12
#define PG_STRIDE 12288  // 256*48 halves per timestep
#define X3_TB 16         // padded halves per (t,b)

typedef __fp16 fp16x2 __attribute__((ext_vector_type(2)));

// ---------- helpers ----------
#if __has_builtin(__builtin_amdgcn_exp2f)
#define EXP2F(x) __builtin_amdgcn_exp2f(x)
#else
#define EXP2F(x) exp2f(x)
#endif
#if __has_builtin(__builtin_amdgcn_rcpf)
#define RCPF(x) __builtin_amdgcn_rcpf(x)
#else
#define RCPF(x) (1.0f / (x))
#endif

__device__ __forceinline__ unsigned rlu(unsigned v, int lane) {
#if __has_builtin(__builtin_amdgcn_readlane)
  return (unsigned)__builtin_amdgcn_readlane((int)v, lane);
#else
  return (unsigned)__shfl((int)v, lane, 64);
#endif
}

template <int Q>
__device__ __forceinline__ float qb(float v) {
#if __has_builtin(__builtin_amdgcn_mov_dpp)
  return __int_as_float(__builtin_amdgcn_mov_dpp(__float_as_int(v), Q * 0x55, 0xF, 0xF, true));
#else
  return __shfl(v, (threadIdx.x & ~3) | Q, 64);
#endif
}

// lane i <- lane i-4 within 16-lane row
__device__ __forceinline__ float row_shr4(float v) {
#if __has_builtin(__builtin_amdgcn_mov_dpp)
  return __int_as_float(__builtin_amdgcn_mov_dpp(__float_as_int(v), 0x114, 0xF, 0xF, true));
#else
  return __shfl(v, (threadIdx.x & 63) - 4, 64);
#endif
}

__device__ __forceinline__ float nl_gate(float x, float kq, float c1, float c0) {
  float e = EXP2F(kq * x);
  float r = RCPF(1.0f + e);
  return fmaf(c1, r, c0);
}
__device__ __forceinline__ float tanh_fast(float x) {
  float e = EXP2F(-2.8853900817779268f * x);
  float r = RCPF(1.0f + e);
  return fmaf(2.0f, r, -1.0f);
}

__device__ __forceinline__ float h16tof(unsigned short u) {
  union { unsigned short s; _Float16 h; } c; c.s = u; return (float)c.h;
}
__device__ __forceinline__ unsigned short f16bits(float f) {
  union { unsigned short s; _Float16 h; } c; c.h = (_Float16)f; return c.s;
}
__device__ __forceinline__ float h16lo(unsigned u) {
  union { unsigned short s; _Float16 h; } c; c.s = (unsigned short)(u & 0xffffu); return (float)c.h;
}
__device__ __forceinline__ float h16hi(unsigned u) {
  union { unsigned short s; _Float16 h; } c; c.s = (unsigned short)(u >> 16); return (float)c.h;
}
__device__ __forceinline__ unsigned pk16(float a, float b) {
#if __has_builtin(__builtin_amdgcn_cvt_pkrtz)
  fp16x2 h = __builtin_amdgcn_cvt_pkrtz(a, b);
  return __builtin_bit_cast(unsigned, h);
#else
  return (unsigned)f16bits(a) | ((unsigned)f16bits(b) << 16);
#endif
}
__device__ __forceinline__ unsigned plo(unsigned a, unsigned b) { return (a & 0xffffu) | (b << 16); }
__device__ __forceinline__ unsigned phi(unsigned a, unsigned b) { return (a >> 16) | (b & 0xffff0000u); }

__device__ __forceinline__ float dot2acc(unsigned a, unsigned b, float c) {
#if __has_builtin(__builtin_amdgcn_fdot2)
  return __builtin_amdgcn_fdot2(__builtin_bit_cast(fp16x2, a), __builtin_bit_cast(fp16x2, b), c, false);
#else
  return fmaf(h16lo(a), h16lo(b), fmaf(h16hi(a), h16hi(b), c));
#endif
}

// 12-dot as two 3-deep dot2 chains
__device__ __forceinline__ float dot33(const unsigned* w, const unsigned* h, float init) {
  float e = dot2acc(w[0], h[0], init);
  e = dot2acc(w[1], h[1], e);
  e = dot2acc(w[2], h[2], e);
  float o = dot2acc(w[3], h[3], 0.f);
  o = dot2acc(w[4], h[4], o);
  o = dot2acc(w[5], h[5], o);
  return e + o;
}
// 12-dot as one 6-deep chain (paired with another for a 24-dot)
__device__ __forceinline__ float dot6c(const unsigned* w, const unsigned* h, float init) {
  float a = dot2acc(w[0], h[0], init);
  a = dot2acc(w[1], h[1], a);
  a = dot2acc(w[2], h[2], a);
  a = dot2acc(w[3], h[3], a);
  a = dot2acc(w[4], h[4], a);
  a = dot2acc(w[5], h[5], a);
  return a;
}

// gate nonlinearity + c/h update (i,f,g,o quad-broadcast via DPP)
__device__ __forceinline__ float nlup(float av, float& cv, float kq, float c1, float c0) {
  float n = nl_gate(av, kq, c1, c0);
  float si = qb<0>(n), sf = qb<1>(n), tg = qb<2>(n), so = qb<3>(n);
  cv = fmaf(sf, cv, si * tg);
  return so * tanh_fast(cv);
}
// pack h into 6 uniform f16x2 pairs: row_shr4 + pkrtz, readlane from lanes 4,12,..,44
__device__ __forceinline__ void packb(float hq, unsigned* hp) {
  float sh = row_shr4(hq);
  unsigned pkv = pk16(sh, hq);
  hp[0] = rlu(pkv, 4);  hp[1] = rlu(pkv, 12); hp[2] = rlu(pkv, 20);
  hp[3] = rlu(pkv, 28); hp[4] = rlu(pkv, 36); hp[5] = rlu(pkv, 44);
}

// ============================================================================
// Kernel 0: pregate  pg[t][b][lane48] = f16( bih0+bhh0 + Wih0 . x[b][t] )
// ============================================================================
__global__ __launch_bounds__(64, 4) void pregate_kernel(
    const float* __restrict__ mfcc, const float* __restrict__ Wih,
    const float* __restrict__ bih, const float* __restrict__ bhh,
    unsigned short* __restrict__ pg) {
  const int b = blockIdx.x & 255;
  const int tc = blockIdx.x >> 8;  // 0..7, chunks of 128 t
  const int lane = threadIdx.x;
  const int j = lane >> 2, q = lane & 3;
  const int jj = (j < HDIM) ? j : (HDIM - 1);
  const int g = q * HDIM + jj;
  float w[HDIM];
#pragma unroll
  for (int m = 0; m < HDIM; ++m) w[m] = Wih[g * HDIM + m];
  const float bias = bih[g] + bhh[g];
  const bool wr = (lane < 48);
  const float* xb = mfcc + (b * T_LEN + tc * 128) * HDIM;
  unsigned short* out = pg + (unsigned)(tc * 128 * NBATCH + b) * 48 + lane;
#pragma unroll 2
  for (int t = 0; t < 128; ++t) {
    float acc = bias;
#pragma unroll
    for (int d = 0; d < HDIM; ++d) acc = fmaf(w[d], xb[d], acc);
    if (wr) *out = f16bits(acc);
    xb += HDIM;
    out += PG_STRIDE;
  }
}

// ============================================================================
// Kernel 1: 3-layer LSTM, 1 wave per batch element, layers software-pipelined
// within the wave (layer l computes step s-l). All state f16-packed:
// h vectors live as 6 uniform f16x2 SGPR pairs (readlane-broadcast), weights
// pre-packed f16x2 in VGPRs, dots via v_dot2_f32_f16. No LDS, no barriers.
// ============================================================================
__global__ __launch_bounds__(64, 1) void lstm3_kernel(
    const unsigned short* __restrict__ pg,
    const float* __restrict__ Wih, const float* __restrict__ Whh,
    const float* __restrict__ bih, const float* __restrict__ bhh,
    unsigned short* __restrict__ x3) {
  const int b = blockIdx.x;
  const int lane = threadIdx.x & 63;
  const int j = lane >> 2, q = lane & 3;
  const int jj = (j < HDIM) ? j : (HDIM - 1);
  const int g = q * HDIM + jj;

  unsigned whh0p[6], wih1p[6], whh1p[6], wih2p[6], whh2p[6];
#pragma unroll
  for (int m = 0; m < 6; ++m) {
    whh0p[m] = pk16(Whh[g * HDIM + 2 * m], Whh[g * HDIM + 2 * m + 1]);
    wih1p[m] = pk16(Wih[(48 + g) * HDIM + 2 * m], Wih[(48 + g) * HDIM + 2 * m + 1]);
    whh1p[m] = pk16(Whh[(48 + g) * HDIM + 2 * m], Whh[(48 + g) * HDIM + 2 * m + 1]);
    wih2p[m] = pk16(Wih[(96 + g) * HDIM + 2 * m], Wih[(96 + g) * HDIM + 2 * m + 1]);
    whh2p[m] = pk16(Whh[(96 + g) * HDIM + 2 * m], Whh[(96 + g) * HDIM + 2 * m + 1]);
  }
  const float bias1 = bih[48 + g] + bhh[48 + g];
  const float bias2 = bih[96 + g] + bhh[96 + g];

  const float kq = (q == 2) ? -2.8853900817779268f : -1.4426950408889634f;
  const float c1c = (q == 2) ? 2.0f : 1.0f;
  const float c0c = (q == 2) ? -1.0f : 0.0f;

  float c0v = 0.f, c1v = 0.f, c2v = 0.f;
  unsigned h0p[6] = {0, 0, 0, 0, 0, 0};
  unsigned h1p[6] = {0, 0, 0, 0, 0, 0};
  unsigned h2p[6] = {0, 0, 0, 0, 0, 0};

  const bool writer = (q == 0) && (j < HDIM);
  unsigned short* x3w = x3 + b * X3_TB + jj;
  const unsigned short* pgl = pg + (unsigned)b * 48 + lane;

  unsigned short r0 = pgl[0];
  unsigned short r1 = pgl[PG_STRIDE];
  unsigned short r2 = pgl[2 * PG_STRIDE];
  unsigned short r3 = pgl[3 * PG_STRIDE];
  pgl += 4 * PG_STRIDE;

// interior superstep: L0 step s, L1 step s-1, L2 step s-2 (all a's computed
// on pre-update h states, then the three tails update states)
#define STEP(RAW)                                                   \
  {                                                                 \
    float a0 = dot33(whh0p, h0p, h16tof(RAW));                      \
    float a1 = dot6c(wih1p, h0p, bias1) + dot6c(whh1p, h1p, 0.f);   \
    float a2 = dot6c(wih2p, h1p, bias2) + dot6c(whh2p, h2p, 0.f);   \
    float hq0 = nlup(a0, c0v, kq, c1c, c0c);                        \
    float hq1 = nlup(a1, c1v, kq, c1c, c0c);                        \
    float hq2 = nlup(a2, c2v, kq, c1c, c0c);                        \
    packb(hq0, h0p);                                                \
    packb(hq1, h1p);                                                \
    packb(hq2, h2p);                                                \
    if (writer) *x3w = f16bits(hq2);                                \
    x3w += NBATCH * X3_TB;                                          \
  }

  // s=0: L0 only (all states zero -> a0 = pregate)
  {
    float hq0 = nlup(h16tof(r0), c0v, kq, c1c, c0c);
    packb(hq0, h0p);
  }
  // s=1: L0 + L1 (h1 zero -> skip whh1 dots)
  {
    float a0 = dot33(whh0p, h0p, h16tof(r1));
    float a1 = dot6c(wih1p, h0p, bias1);
    float hq0 = nlup(a0, c0v, kq, c1c, c0c);
    float hq1 = nlup(a1, c1v, kq, c1c, c0c);
    packb(hq0, h0p);
    packb(hq1, h1p);
  }
  // s = 2..1023: branch-free interior, x2 unroll, pg prefetch distance 2
  for (int it = 0; it < 511; ++it) {
    unsigned short n0 = pgl[0];
    unsigned short n1 = pgl[PG_STRIDE];
    pgl += (it < 509) ? 2 * PG_STRIDE : 0;  // clamp: stay in bounds
    STEP(r2)
    STEP(r3)
    r2 = n0; r3 = n1;
  }
  // s=1024: L1 step 1023 + L2 step 1022
  {
    float a1 = dot6c(wih1p, h0p, bias1) + dot6c(whh1p, h1p, 0.f);
    float a2 = dot6c(wih2p, h1p, bias2) + dot6c(whh2p, h2p, 0.f);
    float hq1 = nlup(a1, c1v, kq, c1c, c0c);
    float hq2 = nlup(a2, c2v, kq, c1c, c0c);
    packb(hq1, h1p);
    packb(hq2, h2p);
    if (writer) *x3w = f16bits(hq2);
    x3w += NBATCH * X3_TB;
  }
  // s=1025: L2 step 1023
  {
    float a2 = dot6c(wih2p, h1p, bias2) + dot6c(whh2p, h2p, 0.f);
    float hq2 = nlup(a2, c2v, kq, c1c, c0c);
    if (writer) *x3w = f16bits(hq2);
  }
#undef STEP
}

// ============================================================================
// Kernel 2: per-timestep MLP + batch BN + lambda projection. 1 block / t.
// f16 staging, v_dot2_f32_f16 fc2 inner loop (k-paired).
// ============================================================================
__global__ __launch_bounds__(256, 2) void mlp_out_kernel(
    const unsigned short* __restrict__ x3, const float* __restrict__ mfcc,
    const float* __restrict__ w1, const float* __restrict__ g1,
    const float* __restrict__ be1, const float* __restrict__ w2,
    const float* __restrict__ g2, const float* __restrict__ be2,
    const float* __restrict__ w3, const float* __restrict__ b3,
    const float* __restrict__ WI, float* __restrict__ outp) {
  __shared__ __align__(16) unsigned char smem[55296];
  unsigned short* h1 = (unsigned short*)smem;        // [64][256] f16
  unsigned* w2p = (unsigned*)(smem + 32768);         // [32][128] k-paired f16x2
  float* p3 = (float*)smem;                          // [8][256][6] (alias, 48KB)
  float* w3s = (float*)(smem + 49152);               // [6][128]
  float* stp = (float*)(smem + 52224);               // stat partials
  float* scsh = (float*)(smem + 54272);              // [128][2]

  const int t = blockIdx.x;
  const int tid = threadIdx.x;

  // ---- phase 1: stage w2 k-paired + w3 ----
  for (int i = tid; i < 4096; i += 256) {
    int kp = i >> 7, c = i & 127;
    w2p[kp * 128 + c] = pk16(w2[c * 64 + 2 * kp], w2[c * 64 + 2 * kp + 1]);
  }
  for (int i = tid; i < 768; i += 256) w3s[i] = w3[i];

  // ---- phase 2: fc1 (bias cancels under BN); thread = one b ----
  {
    const unsigned short* xp = x3 + t * (NBATCH * X3_TB) + tid * X3_TB;
    uint2 u0 = ((const uint2*)xp)[0];
    uint2 u1 = ((const uint2*)xp)[1];
    uint2 u2 = ((const uint2*)xp)[2];
    const float x[HDIM] = {h16lo(u0.x), h16hi(u0.x), h16lo(u0.y), h16hi(u0.y),
                           h16lo(u1.x), h16hi(u1.x), h16lo(u1.y), h16hi(u1.y),
                           h16lo(u2.x), h16hi(u2.x), h16lo(u2.y), h16hi(u2.y)};
#pragma unroll 8
    for (int ch = 0; ch < 64; ++ch) {
      float a = 0.f;
#pragma unroll
      for (int d = 0; d < HDIM; ++d) a = fmaf(w1[ch * HDIM + d], x[d], a);
      h1[ch * 256 + tid] = f16bits(a);
    }
  }
  __syncthreads();

  // ---- phase 3: BN1 stats over b (on stored f16 values) ----
  {
    const int ch = tid & 63, grp = tid >> 6;
    const uint4* rp = (const uint4*)(h1 + ch * 256 + grp * 64);
    float s = 0.f, sq = 0.f;
#pragma unroll
    for (int i = 0; i < 8; ++i) {
      uint4 v = rp[(i + ch) & 7];
      float f0 = h16lo(v.x), f1 = h16hi(v.x), f2 = h16lo(v.y), f3 = h16hi(v.y);
      float f4 = h16lo(v.z), f5 = h16hi(v.z), f6 = h16lo(v.w), f7 = h16hi(v.w);
      s += ((f0 + f1) + (f2 + f3)) + ((f4 + f5) + (f6 + f7));
      sq = fmaf(f0, f0, sq); sq = fmaf(f1, f1, sq);
      sq = fmaf(f2, f2, sq); sq = fmaf(f3, f3, sq);
      sq = fmaf(f4, f4, sq); sq = fmaf(f5, f5, sq);
      sq = fmaf(f6, f6, sq); sq = fmaf(f7, f7, sq);
    }
    stp[(ch * 4 + grp) * 2] = s;
    stp[(ch * 4 + grp) * 2 + 1] = sq;
  }
  __syncthreads();
  if (tid < 64) {
    float s = 0.f, sq = 0.f;
#pragma unroll
    for (int gg = 0; gg < 4; ++gg) {
      s += stp[(tid * 4 + gg) * 2];
      sq += stp[(tid * 4 + gg) * 2 + 1];
    }
    float mu = s * (1.f / 256.f);
    float var = fmaf(-mu, mu, sq * (1.f / 256.f));
    float sc = g1[tid] * rsqrtf(var + 1e-5f);
    scsh[tid * 2] = sc;
    scsh[tid * 2 + 1] = fmaf(-sc, mu, be1[tid]);
  }
  __syncthreads();
  // ---- phase 3c: apply BN1 + relu in place ----
  {
    const int ch = tid & 63, grp = tid >> 6;
    const float sc = scsh[ch * 2], sh = scsh[ch * 2 + 1];
    uint4* rp = (uint4*)(h1 + ch * 256 + grp * 64);
#pragma unroll
    for (int i = 0; i < 8; ++i) {
      uint4 v = rp[(i + ch) & 7];
      float f0 = fmaxf(fmaf(sc, h16lo(v.x), sh), 0.f);
      float f1 = fmaxf(fmaf(sc, h16hi(v.x), sh), 0.f);
      float f2 = fmaxf(fmaf(sc, h16lo(v.y), sh), 0.f);
      float f3 = fmaxf(fmaf(sc, h16hi(v.y), sh), 0.f);
      float f4 = fmaxf(fmaf(sc, h16lo(v.z), sh), 0.f);
      float f5 = fmaxf(fmaf(sc, h16hi(v.z), sh), 0.f);
      float f6 = fmaxf(fmaf(sc, h16lo(v.w), sh), 0.f);
      float f7 = fmaxf(fmaf(sc, h16hi(v.w), sh), 0.f);
      v.x = pk16(f0, f1); v.y = pk16(f2, f3);
      v.z = pk16(f4, f5); v.w = pk16(f6, f7);
      rp[(i + ch) & 7] = v;
    }
  }
  __syncthreads();

  // ---- phase 4: fc2, 8b x 16c per thread, dot2 over k-pairs ----
  const int tb = tid & 31, tc = tid >> 5;
  const int b0 = tb * 8, cc0 = tc * 16;
  float acc[8][16];
#pragma unroll
  for (int bi = 0; bi < 8; ++bi)
#pragma unroll
    for (int ci = 0; ci < 16; ++ci) acc[bi][ci] = 0.f;

  for (int kp = 0; kp < 32; ++kp) {
    uint4 aL = *(const uint4*)(h1 + (2 * kp) * 256 + b0);
    uint4 aH = *(const uint4*)(h1 + (2 * kp + 1) * 256 + b0);
    const unsigned* wrow = w2p + kp * 128 + cc0;
    uint4 wA = ((const uint4*)wrow)[0];
    uint4 wB = ((const uint4*)wrow)[1];
    uint4 wC = ((const uint4*)wrow)[2];
    uint4 wD = ((const uint4*)wrow)[3];
    unsigned ap[8];
    ap[0] = plo(aL.x, aH.x); ap[1] = phi(aL.x, aH.x);
    ap[2] = plo(aL.y, aH.y); ap[3] = phi(aL.y, aH.y);
    ap[4] = plo(aL.z, aH.z); ap[5] = phi(aL.z, aH.z);
    ap[6] = plo(aL.w, aH.w); ap[7] = phi(aL.w, aH.w);
    const unsigned wp[16] = {wA.x, wA.y, wA.z, wA.w, wB.x, wB.y, wB.z, wB.w,
                             wC.x, wC.y, wC.z, wC.w, wD.x, wD.y, wD.z, wD.w};
#pragma unroll
    for (int bi = 0; bi < 8; ++bi)
#pragma unroll
      for (int ci = 0; ci < 16; ++ci) acc[bi][ci] = dot2acc(ap[bi], wp[ci], acc[bi][ci]);
  }

  // ---- phase 5: BN2 stats (shuffle-reduce over tb) ----
  {
    float sv[16], qv[16];
#pragma unroll
    for (int ci = 0; ci < 16; ++ci) {
      float s = 0.f, sq = 0.f;
#pragma unroll
      for (int bi = 0; bi < 8; ++bi) {
        s += acc[bi][ci];
        sq = fmaf(acc[bi][ci], acc[bi][ci], sq);
      }
      sv[ci] = s; qv[ci] = sq;
    }
#pragma unroll
    for (int m = 1; m <= 16; m <<= 1) {
#pragma unroll
      for (int ci = 0; ci < 16; ++ci) {
        sv[ci] += __shfl_xor(sv[ci], m, 64);
        qv[ci] += __shfl_xor(qv[ci], m, 64);
      }
    }
    if (tb == 0) {
#pragma unroll
      for (int ci = 0; ci < 16; ++ci) {
        stp[(cc0 + ci) * 2] = sv[ci];
        stp[(cc0 + ci) * 2 + 1] = qv[ci];
      }
    }
  }
  __syncthreads();
  if (tid < 128) {
    float mu = stp[tid * 2] * (1.f / 256.f);
    float var = fmaf(-mu, mu, stp[tid * 2 + 1] * (1.f / 256.f));
    float sc = g2[tid] * rsqrtf(var + 1e-5f);
    scsh[tid * 2] = sc;
    scsh[tid * 2 + 1] = fmaf(-sc, mu, be2[tid]);
  }
  __syncthreads();
#pragma unroll
  for (int ci = 0; ci < 16; ++ci) {
    const float sc = scsh[(cc0 + ci) * 2], sh = scsh[(cc0 + ci) * 2 + 1];
#pragma unroll
    for (int bi = 0; bi < 8; ++bi)
      acc[bi][ci] = fmaxf(fmaf(sc, acc[bi][ci], sh), 0.f);
  }

  // ---- phase 6: fc3 partials over this thread's 16 channels ----
  {
    float lam[8][6];
#pragma unroll
    for (int bi = 0; bi < 8; ++bi)
#pragma unroll
      for (int k6 = 0; k6 < 6; ++k6) lam[bi][k6] = 0.f;
#pragma unroll
    for (int ci = 0; ci < 16; ++ci) {
      float wv[6];
#pragma unroll
      for (int k6 = 0; k6 < 6; ++k6) wv[k6] = w3s[k6 * 128 + cc0 + ci];
#pragma unroll
      for (int bi = 0; bi < 8; ++bi)
#pragma unroll
        for (int k6 = 0; k6 < 6; ++k6)
          lam[bi][k6] = fmaf(acc[bi][ci], wv[k6], lam[bi][k6]);
    }
#pragma unroll
    for (int bi = 0; bi < 8; ++bi)
#pragma unroll
      for (int k6 = 0; k6 < 6; ++k6)
        p3[(tc * 256 + b0 + bi) * 6 + k6] = lam[bi][k6];
  }
  __syncthreads();

  // ---- phase 7: reduce lambda, apply projection, write out ----
  {
    float lm[6];
#pragma unroll
    for (int k6 = 0; k6 < 6; ++k6) lm[k6] = b3[k6];
#pragma unroll
    for (int tcc = 0; tcc < 8; ++tcc)
#pragma unroll
      for (int k6 = 0; k6 < 6; ++k6) lm[k6] += p3[(tcc * 256 + tid) * 6 + k6];

    const float4* mp = (const float4*)(mfcc + (tid * T_LEN + t) * HDIM);
    float4 m0 = mp[0], m1 = mp[1], m2 = mp[2];
    const float x[HDIM] = {m0.x, m0.y, m0.z, m0.w, m1.x, m1.y,
                           m1.z, m1.w, m2.x, m2.y, m2.z, m2.w};
    float o[HDIM];
#pragma unroll
    for (int e = 0; e < HDIM; ++e) o[e] = x[e];
#pragma unroll
    for (int k6 = 0; k6 < 6; ++k6) {
      float pk[HDIM];
#pragma unroll
      for (int e = 0; e < HDIM; ++e) pk[e] = 0.f;
#pragma unroll
      for (int d = 0; d < HDIM; ++d)
#pragma unroll
        for (int e = 0; e < HDIM; ++e)
          pk[e] = fmaf(x[d], WI[(k6 * HDIM + d) * HDIM + e], pk[e]);
#pragma unroll
      for (int e = 0; e < HDIM; ++e) o[e] = fmaf(lm[k6], pk[e], o[e]);
    }
    float4* op4 = (float4*)(outp + (tid * T_LEN + t) * HDIM);
    op4[0] = make_float4(o[0], o[1], o[2], o[3]);
    op4[1] = make_float4(o[4], o[5], o[6], o[7]);
    op4[2] = make_float4(o[8], o[9], o[10], o[11]);
  }
}

// ============================================================================
extern "C" void kernel_launch(void* const* d_in, const int* in_sizes, int n_in,
                              void* d_out, int out_size, void* d_ws, size_t ws_size,
                              hipStream_t stream) {
  const float* mfcc = (const float*)d_in[0];
  const float* Wih = (const float*)d_in[1];
  const float* Whh = (const float*)d_in[2];
  const float* bih = (const float*)d_in[3];
  const float* bhh = (const float*)d_in[4];
  const float* w1 = (const float*)d_in[5];
  const float* g1 = (const float*)d_in[7];
  const float* be1 = (const float*)d_in[8];
  const float* w2 = (const float*)d_in[9];
  const float* g2 = (const float*)d_in[11];
  const float* be2 = (const float*)d_in[12];
  const float* w3 = (const float*)d_in[13];
  const float* b3 = (const float*)d_in[14];
  const float* WI = (const float*)d_in[15];

  // ws: pregate f16 [1024][256][48] = 25,165,824 B ; x3 f16 [1024][256][16] = 8,388,608 B
  unsigned short* pg = (unsigned short*)d_ws;
  unsigned short* x3 = (unsigned short*)((char*)d_ws + 25165824);
  float* out = (float*)d_out;

  hipLaunchKernelGGL(pregate_kernel, dim3(2048), dim3(64), 0, stream,
                     mfcc, Wih, bih, bhh, pg);
  hipLaunchKernelGGL(lstm3_kernel, dim3(NBATCH), dim3(64), 0, stream,
                     pg, Wih, Whh, bih, bhh, x3);
  hipLaunchKernelGGL(mlp_out_kernel, dim3(T_LEN), dim3(256), 0, stream,
                     x3, mfcc, w1, g1, be1, w2, g2, be2, w3, b3, WI, out);
}

// Round 6
// 353.339 us; speedup vs baseline: 1.4291x; 1.2528x over previous
//
#include <hip/hip_runtime.h>

#define T_LEN 1024
#define NBATCH 256
#define HDIM 12
#define PAIR_STRIDE 12288  // 256*48 dwords per timestep-pair
#define X3_TB 16           // padded halves per (t,b)

typedef __fp16 fp16x2 __attribute__((ext_vector_type(2)));

// ---------- helpers ----------
#if __has_builtin(__builtin_amdgcn_exp2f)
#define EXP2F(x) __builtin_amdgcn_exp2f(x)
#else
#define EXP2F(x) exp2f(x)
#endif
#if __has_builtin(__builtin_amdgcn_rcpf)
#define RCPF(x) __builtin_amdgcn_rcpf(x)
#else
#define RCPF(x) (1.0f / (x))
#endif

#define KSIG -1.4426950408889634f
#define KTAN -2.8853900817779268f

__device__ __forceinline__ unsigned rlu(unsigned v, int lane) {
#if __has_builtin(__builtin_amdgcn_readlane)
  return (unsigned)__builtin_amdgcn_readlane((int)v, lane);
#else
  return (unsigned)__shfl((int)v, lane, 64);
#endif
}

template <int Q>
__device__ __forceinline__ float qb(float v) {
#if __has_builtin(__builtin_amdgcn_mov_dpp)
  return __int_as_float(__builtin_amdgcn_mov_dpp(__float_as_int(v), Q * 0x55, 0xF, 0xF, true));
#else
  return __shfl(v, (threadIdx.x & ~3) | Q, 64);
#endif
}

// lane i <- lane i-4 within 16-lane row
__device__ __forceinline__ float row_shr4(float v) {
#if __has_builtin(__builtin_amdgcn_mov_dpp)
  return __int_as_float(__builtin_amdgcn_mov_dpp(__float_as_int(v), 0x114, 0xF, 0xF, true));
#else
  return __shfl(v, (threadIdx.x & 63) - 4, 64);
#endif
}

__device__ __forceinline__ float h16tof(unsigned short u) {
  union { unsigned short s; _Float16 h; } c; c.s = u; return (float)c.h;
}
__device__ __forceinline__ unsigned short f16bits(float f) {
  union { unsigned short s; _Float16 h; } c; c.h = (_Float16)f; return c.s;
}
__device__ __forceinline__ float h16lo(unsigned u) {
  union { unsigned short s; _Float16 h; } c; c.s = (unsigned short)(u & 0xffffu); return (float)c.h;
}
__device__ __forceinline__ float h16hi(unsigned u) {
  union { unsigned short s; _Float16 h; } c; c.s = (unsigned short)(u >> 16); return (float)c.h;
}
__device__ __forceinline__ unsigned pk16(float a, float b) {
#if __has_builtin(__builtin_amdgcn_cvt_pkrtz)
  fp16x2 h = __builtin_amdgcn_cvt_pkrtz(a, b);
  return __builtin_bit_cast(unsigned, h);
#else
  return (unsigned)f16bits(a) | ((unsigned)f16bits(b) << 16);
#endif
}

__device__ __forceinline__ float dot2acc(unsigned a, unsigned b, float c) {
#if __has_builtin(__builtin_amdgcn_fdot2)
  return __builtin_amdgcn_fdot2(__builtin_bit_cast(fp16x2, a), __builtin_bit_cast(fp16x2, b), c, false);
#else
  return fmaf(h16lo(a), h16lo(b), fmaf(h16hi(a), h16hi(b), c));
#endif
}

// 3-deep dot2 chain (6 MACs)
__device__ __forceinline__ float d3(const unsigned* w, const unsigned* h, float init) {
  float a = dot2acc(w[0], h[0], init);
  a = dot2acc(w[1], h[1], a);
  return dot2acc(w[2], h[2], a);
}

// gate nonlin (prescaled input) + c/h update; i,f,g,o quad-broadcast via DPP
__device__ __forceinline__ float nlup(float av, float& cv, float c1, float c0) {
  float e = EXP2F(av);
  float n = fmaf(c1, RCPF(1.f + e), c0);
  float si = qb<0>(n), sf = qb<1>(n), tg = qb<2>(n), so = qb<3>(n);
  cv = fmaf(sf, cv, si * tg);
  float e2 = EXP2F(KTAN * cv);
  return so * fmaf(2.f, RCPF(1.f + e2), -1.f);
}
// pack h into 6 uniform f16x2 pairs
__device__ __forceinline__ void packb(float hq, unsigned* hp) {
  float sh = row_shr4(hq);
  unsigned pkv = pk16(sh, hq);
  hp[0] = rlu(pkv, 4);  hp[1] = rlu(pkv, 12); hp[2] = rlu(pkv, 20);
  hp[3] = rlu(pkv, 28); hp[4] = rlu(pkv, 36); hp[5] = rlu(pkv, 44);
}

// ============================================================================
// Kernel 0: (a) pregate pairs pg2[t2][b][lane48] = f16x2 of kq-scaled
//           (bih0+bhh0 + Wih0.x) for steps (2*t2, 2*t2+1); (b) w2 pre-pack.
// ============================================================================
__global__ __launch_bounds__(64, 4) void pregate_kernel(
    const float* __restrict__ mfcc, const float* __restrict__ Wih,
    const float* __restrict__ bih, const float* __restrict__ bhh,
    const float* __restrict__ w2, unsigned* __restrict__ pg2,
    unsigned* __restrict__ w2pk) {
  if (blockIdx.x >= 2048) {  // w2 pack: [32 kp][128 c] <- w2[c][2kp..2kp+1]
    for (int i = (blockIdx.x - 2048) * 64 + threadIdx.x; i < 4096; i += 512) {
      int kp = i >> 7, c = i & 127;
      float2 v = ((const float2*)w2)[c * 32 + kp];
      w2pk[i] = pk16(v.x, v.y);
    }
    return;
  }
  const int b = blockIdx.x & 255;
  const int tc = blockIdx.x >> 8;  // 0..7, chunks of 64 pairs
  const int lane = threadIdx.x;
  const int j = lane >> 2, q = lane & 3;
  const int jj = (j < HDIM) ? j : (HDIM - 1);
  const int g = q * HDIM + jj;
  const float kqv = (q == 2) ? KTAN : KSIG;
  float w[HDIM];
#pragma unroll
  for (int m = 0; m < HDIM; ++m) w[m] = kqv * Wih[g * HDIM + m];
  const float bias = kqv * (bih[g] + bhh[g]);
  const bool wr = (lane < 48);
  const float* xb = mfcc + (b * T_LEN + tc * 128) * HDIM;
  unsigned* out = pg2 + (unsigned)(tc * 64 * NBATCH + b) * 48 + lane;
  for (int tp = 0; tp < 64; ++tp) {
    float a0 = bias, a1 = bias;
#pragma unroll
    for (int d = 0; d < HDIM; ++d) {
      a0 = fmaf(w[d], xb[d], a0);
      a1 = fmaf(w[d], xb[HDIM + d], a1);
    }
    if (wr) *out = pk16(a0, a1);
    xb += 2 * HDIM;
    out += PAIR_STRIDE;
  }
}

// ============================================================================
// Kernel 1: 3-layer LSTM, 1 wave per batch element, layers software-pipelined
// (layer l computes step s-l). f16-packed state/weights (prescaled), dots via
// v_dot2_f32_f16, pg pair-loads with 4-step prefetch, unconditional stores.
// ============================================================================
__global__ __launch_bounds__(64, 1) void lstm3_kernel(
    const unsigned* __restrict__ pg2,
    const float* __restrict__ Wih, const float* __restrict__ Whh,
    const float* __restrict__ bih, const float* __restrict__ bhh,
    unsigned short* __restrict__ x3) {
  const int b = blockIdx.x;
  const int lane = threadIdx.x & 63;
  const int j = lane >> 2, q = lane & 3;
  const int jj = (j < HDIM) ? j : (HDIM - 1);
  const int g = q * HDIM + jj;
  const float kqv = (q == 2) ? KTAN : KSIG;
  const float c1c = (q == 2) ? 2.0f : 1.0f;
  const float c0c = (q == 2) ? -1.0f : 0.0f;

  unsigned whh0p[6], wih1p[6], whh1p[6], wih2p[6], whh2p[6];
#pragma unroll
  for (int m = 0; m < 6; ++m) {
    whh0p[m] = pk16(kqv * Whh[g * HDIM + 2 * m], kqv * Whh[g * HDIM + 2 * m + 1]);
    wih1p[m] = pk16(kqv * Wih[(48 + g) * HDIM + 2 * m], kqv * Wih[(48 + g) * HDIM + 2 * m + 1]);
    whh1p[m] = pk16(kqv * Whh[(48 + g) * HDIM + 2 * m], kqv * Whh[(48 + g) * HDIM + 2 * m + 1]);
    wih2p[m] = pk16(kqv * Wih[(96 + g) * HDIM + 2 * m], kqv * Wih[(96 + g) * HDIM + 2 * m + 1]);
    whh2p[m] = pk16(kqv * Whh[(96 + g) * HDIM + 2 * m], kqv * Whh[(96 + g) * HDIM + 2 * m + 1]);
  }
  const float bias1 = kqv * (bih[48 + g] + bhh[48 + g]);
  const float bias2 = kqv * (bih[96 + g] + bhh[96 + g]);

  float c0v = 0.f, c1v = 0.f, c2v = 0.f;
  unsigned h0p[6] = {0, 0, 0, 0, 0, 0};
  unsigned h1p[6] = {0, 0, 0, 0, 0, 0};
  unsigned h2p[6] = {0, 0, 0, 0, 0, 0};

  // lanes >=48 mirror the (q, j=11) lane's pregate stream
  const int lane_src = (lane < 48) ? lane : (44 + (lane & 3));
  const unsigned* pgl = pg2 + (unsigned)b * 48 + lane_src;
  unsigned short* x3w = x3 + b * X3_TB + jj;  // all lanes store (quad-uniform hq)

  unsigned p0 = pgl[0];               // pair 0 (steps 0,1)
  unsigned pa = pgl[PAIR_STRIDE];     // pair 1
  unsigned pb = pgl[2 * PAIR_STRIDE]; // pair 2
  pgl += 3 * PAIR_STRIDE;

#define STEP(PGF)                                                          \
  {                                                                        \
    float a0 = d3(whh0p, h0p, (PGF)) + d3(whh0p + 3, h0p + 3, 0.f);        \
    float a1 = (d3(wih1p, h0p, bias1) + d3(wih1p + 3, h0p + 3, 0.f)) +     \
               (d3(whh1p, h1p, 0.f) + d3(whh1p + 3, h1p + 3, 0.f));       \
    float a2 = (d3(wih2p, h1p, bias2) + d3(wih2p + 3, h1p + 3, 0.f)) +     \
               (d3(whh2p, h2p, 0.f) + d3(whh2p + 3, h2p + 3, 0.f));       \
    float hq0 = nlup(a0, c0v, c1c, c0c);                                   \
    float hq1 = nlup(a1, c1v, c1c, c0c);                                   \
    float hq2 = nlup(a2, c2v, c1c, c0c);                                   \
    packb(hq0, h0p);                                                       \
    packb(hq1, h1p);                                                       \
    packb(hq2, h2p);                                                       \
    *x3w = f16bits(hq2);                                                   \
    x3w += NBATCH * X3_TB;                                                 \
  }

  // s=0: L0 only (a0 = scaled pregate)
  {
    float hq0 = nlup(h16lo(p0), c0v, c1c, c0c);
    packb(hq0, h0p);
  }
  // s=1: L0 + L1 (h1 zero)
  {
    float a0 = d3(whh0p, h0p, h16hi(p0)) + d3(whh0p + 3, h0p + 3, 0.f);
    float a1 = d3(wih1p, h0p, bias1) + d3(wih1p + 3, h0p + 3, 0.f);
    float hq0 = nlup(a0, c0v, c1c, c0c);
    float hq1 = nlup(a1, c1v, c1c, c0c);
    packb(hq0, h0p);
    packb(hq1, h1p);
  }
  // s=2..1023: 511 pair-iterations, prefetch 2 pairs (4 steps) ahead
  for (int it = 0; it < 511; ++it) {
    unsigned pn = pgl[0];  // pair it+3 (pads 512/513 exist, never consumed)
    pgl += PAIR_STRIDE;
    STEP(h16lo(pa))
    STEP(h16hi(pa))
    pa = pb; pb = pn;
  }
  // s=1024: L1 step 1023 + L2 step 1022
  {
    float a1 = (d3(wih1p, h0p, bias1) + d3(wih1p + 3, h0p + 3, 0.f)) +
               (d3(whh1p, h1p, 0.f) + d3(whh1p + 3, h1p + 3, 0.f));
    float a2 = (d3(wih2p, h1p, bias2) + d3(wih2p + 3, h1p + 3, 0.f)) +
               (d3(whh2p, h2p, 0.f) + d3(whh2p + 3, h2p + 3, 0.f));
    float hq1 = nlup(a1, c1v, c1c, c0c);
    float hq2 = nlup(a2, c2v, c1c, c0c);
    packb(hq1, h1p);
    packb(hq2, h2p);
    *x3w = f16bits(hq2);
    x3w += NBATCH * X3_TB;
  }
  // s=1025: L2 step 1023
  {
    float a2 = (d3(wih2p, h1p, bias2) + d3(wih2p + 3, h1p + 3, 0.f)) +
               (d3(whh2p, h2p, 0.f) + d3(whh2p + 3, h2p + 3, 0.f));
    float hq2 = nlup(a2, c2v, c1c, c0c);
    *x3w = f16bits(hq2);
  }
#undef STEP
}

// ============================================================================
// Kernel 2: per-timestep MLP + batch BN + lambda projection. 1 block / t.
// h1 in LDS as k-paired f16x2 [32 kp][256 b]; w2 pre-packed [32 kp][128 c].
// fc2 reads pairs directly (no repacking). w3 read from global (L2-hot).
// ============================================================================
__global__ __launch_bounds__(256, 2) void mlp_out_kernel(
    const unsigned short* __restrict__ x3, const float* __restrict__ mfcc,
    const float* __restrict__ w1, const float* __restrict__ g1,
    const float* __restrict__ be1, const unsigned* __restrict__ w2pk,
    const float* __restrict__ g2, const float* __restrict__ be2,
    const float* __restrict__ w3, const float* __restrict__ b3,
    const float* __restrict__ WI, float* __restrict__ outp) {
  __shared__ __align__(16) unsigned char smem[52224];
  unsigned* h1p = (unsigned*)smem;            // [32][256] dwords, 32KB
  unsigned* w2p = (unsigned*)(smem + 32768);  // [32][128] dwords, 16KB
  float* p3 = (float*)smem;                   // [8][256][6] f32 alias, 48KB
  float* stp = (float*)(smem + 49152);        // 2KB partials
  float* scsh = (float*)(smem + 51200);       // [128][2] f32, 1KB

  const int t = blockIdx.x;
  const int tid = threadIdx.x;

  // ---- phase 1: stage w2p (coalesced, conflict-free) ----
  for (int i = tid; i < 1024; i += 256)
    ((uint4*)w2p)[i] = ((const uint4*)w2pk)[i];

  // ---- phase 2: fc1 (bias cancels under BN); thread = one b, paired output ----
  {
    const unsigned short* xp = x3 + t * (NBATCH * X3_TB) + tid * X3_TB;
    uint2 u0 = ((const uint2*)xp)[0];
    uint2 u1 = ((const uint2*)xp)[1];
    uint2 u2 = ((const uint2*)xp)[2];
    const float x[HDIM] = {h16lo(u0.x), h16hi(u0.x), h16lo(u0.y), h16hi(u0.y),
                           h16lo(u1.x), h16hi(u1.x), h16lo(u1.y), h16hi(u1.y),
                           h16lo(u2.x), h16hi(u2.x), h16lo(u2.y), h16hi(u2.y)};
#pragma unroll 4
    for (int kp = 0; kp < 32; ++kp) {
      float a0 = 0.f, a1 = 0.f;
#pragma unroll
      for (int d = 0; d < HDIM; ++d) {
        a0 = fmaf(w1[(2 * kp) * HDIM + d], x[d], a0);
        a1 = fmaf(w1[(2 * kp + 1) * HDIM + d], x[d], a1);
      }
      h1p[kp * 256 + tid] = pk16(a0, a1);
    }
  }
  __syncthreads();

  // ---- phase 3: BN1 stats; thread=(kp,seg), 32 b each, xor32 + LDS reduce ----
  {
    const int kp = tid & 31, seg = tid >> 5;
    const uint4* rp = (const uint4*)(h1p + kp * 256 + seg * 32);
    float sl = 0.f, sh = 0.f, ql = 0.f, qh = 0.f;
#pragma unroll
    for (int i = 0; i < 8; ++i) {
      uint4 v = rp[(i + kp) & 7];  // rotate to avoid bank conflicts
      float f0 = h16lo(v.x), f1 = h16hi(v.x), f2 = h16lo(v.y), f3 = h16hi(v.y);
      float f4 = h16lo(v.z), f5 = h16hi(v.z), f6 = h16lo(v.w), f7 = h16hi(v.w);
      sl += (f0 + f2) + (f4 + f6);
      sh += (f1 + f3) + (f5 + f7);
      ql = fmaf(f0, f0, ql); ql = fmaf(f2, f2, ql); ql = fmaf(f4, f4, ql); ql = fmaf(f6, f6, ql);
      qh = fmaf(f1, f1, qh); qh = fmaf(f3, f3, qh); qh = fmaf(f5, f5, qh); qh = fmaf(f7, f7, qh);
    }
    sl += __shfl_xor(sl, 32, 64); sh += __shfl_xor(sh, 32, 64);
    ql += __shfl_xor(ql, 32, 64); qh += __shfl_xor(qh, 32, 64);
    if ((tid & 63) < 32) {
      float* sp = stp + kp * 16 + (tid >> 6) * 4;
      sp[0] = sl; sp[1] = sh; sp[2] = ql; sp[3] = qh;
    }
  }
  __syncthreads();
  if (tid < 64) {
    const int kp = tid >> 1, par = tid & 1;
    float s = 0.f, qq = 0.f;
#pragma unroll
    for (int w = 0; w < 4; ++w) {
      s += stp[kp * 16 + w * 4 + par];
      qq += stp[kp * 16 + w * 4 + 2 + par];
    }
    const int ch = 2 * kp + par;
    float mu = s * (1.f / 256.f);
    float var = fmaf(-mu, mu, qq * (1.f / 256.f));
    float sc = g1[ch] * rsqrtf(var + 1e-5f);
    scsh[ch * 2] = sc;
    scsh[ch * 2 + 1] = fmaf(-sc, mu, be1[ch]);
  }
  __syncthreads();
  // ---- phase 3c: apply BN1 + relu in place (thread = b) ----
  {
    unsigned* cp = h1p + tid;
#pragma unroll 8
    for (int kp = 0; kp < 32; ++kp) {
      unsigned v = cp[kp * 256];
      float fl = fmaxf(fmaf(scsh[kp * 4 + 0], h16lo(v), scsh[kp * 4 + 1]), 0.f);
      float fh = fmaxf(fmaf(scsh[kp * 4 + 2], h16hi(v), scsh[kp * 4 + 3]), 0.f);
      cp[kp * 256] = pk16(fl, fh);
    }
  }
  __syncthreads();

  // ---- phase 4: fc2, 8b x 16c per thread, direct pair reads ----
  const int tb = tid & 31, tc2 = tid >> 5;
  const int b0 = tb * 8, cc0 = tc2 * 16;
  float acc[8][16];
#pragma unroll
  for (int bi = 0; bi < 8; ++bi)
#pragma unroll
    for (int ci = 0; ci < 16; ++ci) acc[bi][ci] = 0.f;

  for (int kp = 0; kp < 32; ++kp) {
    const unsigned* hrow = h1p + kp * 256 + b0;
    uint4 a01 = ((const uint4*)hrow)[0];
    uint4 a23 = ((const uint4*)hrow)[1];
    const unsigned ap[8] = {a01.x, a01.y, a01.z, a01.w, a23.x, a23.y, a23.z, a23.w};
    const unsigned* wrow = w2p + kp * 128 + cc0;
#pragma unroll
    for (int wq = 0; wq < 4; ++wq) {
      uint4 wv = ((const uint4*)wrow)[wq];
      const unsigned ww[4] = {wv.x, wv.y, wv.z, wv.w};
#pragma unroll
      for (int bi = 0; bi < 8; ++bi)
#pragma unroll
        for (int cj = 0; cj < 4; ++cj)
          acc[bi][wq * 4 + cj] = dot2acc(ap[bi], ww[cj], acc[bi][wq * 4 + cj]);
    }
  }

  // ---- phase 5: BN2 stats (shuffle-reduce over tb) ----
  {
    float sv[16], qv[16];
#pragma unroll
    for (int ci = 0; ci < 16; ++ci) {
      float s = 0.f, sq = 0.f;
#pragma unroll
      for (int bi = 0; bi < 8; ++bi) {
        s += acc[bi][ci];
        sq = fmaf(acc[bi][ci], acc[bi][ci], sq);
      }
      sv[ci] = s; qv[ci] = sq;
    }
#pragma unroll
    for (int m = 1; m <= 16; m <<= 1) {
#pragma unroll
      for (int ci = 0; ci < 16; ++ci) {
        sv[ci] += __shfl_xor(sv[ci], m, 64);
        qv[ci] += __shfl_xor(qv[ci], m, 64);
      }
    }
    if (tb == 0) {
#pragma unroll
      for (int ci = 0; ci < 16; ++ci) {
        stp[(cc0 + ci) * 2] = sv[ci];
        stp[(cc0 + ci) * 2 + 1] = qv[ci];
      }
    }
  }
  __syncthreads();
  if (tid < 128) {
    float mu = stp[tid * 2] * (1.f / 256.f);
    float var = fmaf(-mu, mu, stp[tid * 2 + 1] * (1.f / 256.f));
    float sc = g2[tid] * rsqrtf(var + 1e-5f);
    scsh[tid * 2] = sc;
    scsh[tid * 2 + 1] = fmaf(-sc, mu, be2[tid]);
  }
  __syncthreads();

  // ---- phase 6: BN2-apply + relu + fc3 partials (fused) ----
  {
    float lam[8][6];
#pragma unroll
    for (int bi = 0; bi < 8; ++bi)
#pragma unroll
      for (int k6 = 0; k6 < 6; ++k6) lam[bi][k6] = 0.f;
#pragma unroll
    for (int ci = 0; ci < 16; ++ci) {
      const float sc = scsh[(cc0 + ci) * 2], shv = scsh[(cc0 + ci) * 2 + 1];
      float wv6[6];
#pragma unroll
      for (int k6 = 0; k6 < 6; ++k6) wv6[k6] = w3[k6 * 128 + cc0 + ci];
#pragma unroll
      for (int bi = 0; bi < 8; ++bi) {
        float v = fmaxf(fmaf(sc, acc[bi][ci], shv), 0.f);
#pragma unroll
        for (int k6 = 0; k6 < 6; ++k6)
          lam[bi][k6] = fmaf(v, wv6[k6], lam[bi][k6]);
      }
    }
#pragma unroll
    for (int bi = 0; bi < 8; ++bi)
#pragma unroll
      for (int k6 = 0; k6 < 6; ++k6)
        p3[(tc2 * 256 + b0 + bi) * 6 + k6] = lam[bi][k6];
  }
  __syncthreads();

  // ---- phase 7: reduce lambda, apply projection, write out ----
  {
    float lm[6];
#pragma unroll
    for (int k6 = 0; k6 < 6; ++k6) lm[k6] = b3[k6];
#pragma unroll
    for (int tcc = 0; tcc < 8; ++tcc)
#pragma unroll
      for (int k6 = 0; k6 < 6; ++k6) lm[k6] += p3[(tcc * 256 + tid) * 6 + k6];

    const float4* mp = (const float4*)(mfcc + (tid * T_LEN + t) * HDIM);
    float4 m0 = mp[0], m1 = mp[1], m2 = mp[2];
    const float x[HDIM] = {m0.x, m0.y, m0.z, m0.w, m1.x, m1.y,
                           m1.z, m1.w, m2.x, m2.y, m2.z, m2.w};
    float o[HDIM];
#pragma unroll
    for (int e = 0; e < HDIM; ++e) o[e] = x[e];
#pragma unroll
    for (int k6 = 0; k6 < 6; ++k6) {
      float pk[HDIM];
#pragma unroll
      for (int e = 0; e < HDIM; ++e) pk[e] = 0.f;
#pragma unroll
      for (int d = 0; d < HDIM; ++d)
#pragma unroll
        for (int e = 0; e < HDIM; ++e)
          pk[e] = fmaf(x[d], WI[(k6 * HDIM + d) * HDIM + e], pk[e]);
#pragma unroll
      for (int e = 0; e < HDIM; ++e) o[e] = fmaf(lm[k6], pk[e], o[e]);
    }
    float4* op4 = (float4*)(outp + (tid * T_LEN + t) * HDIM);
    op4[0] = make_float4(o[0], o[1], o[2], o[3]);
    op4[1] = make_float4(o[4], o[5], o[6], o[7]);
    op4[2] = make_float4(o[8], o[9], o[10], o[11]);
  }
}

// ============================================================================
extern "C" void kernel_launch(void* const* d_in, const int* in_sizes, int n_in,
                              void* d_out, int out_size, void* d_ws, size_t ws_size,
                              hipStream_t stream) {
  const float* mfcc = (const float*)d_in[0];
  const float* Wih = (const float*)d_in[1];
  const float* Whh = (const float*)d_in[2];
  const float* bih = (const float*)d_in[3];
  const float* bhh = (const float*)d_in[4];
  const float* w1 = (const float*)d_in[5];
  const float* g1 = (const float*)d_in[7];
  const float* be1 = (const float*)d_in[8];
  const float* w2 = (const float*)d_in[9];
  const float* g2 = (const float*)d_in[11];
  const float* be2 = (const float*)d_in[12];
  const float* w3 = (const float*)d_in[13];
  const float* b3 = (const float*)d_in[14];
  const float* WI = (const float*)d_in[15];

  // ws: pg2 dwords [514 pairs][256 b][48] = 25,264,128 B;
  //     x3 f16 [1024][256][16] = 8,388,608 B @ 25,264,128;
  //     w2pk [4096] dwords = 16,384 B @ 33,652,736.
  unsigned* pg2 = (unsigned*)d_ws;
  unsigned short* x3 = (unsigned short*)((char*)d_ws + 25264128);
  unsigned* w2pk = (unsigned*)((char*)d_ws + 33652736);
  float* out = (float*)d_out;

  hipLaunchKernelGGL(pregate_kernel, dim3(2056), dim3(64), 0, stream,
                     mfcc, Wih, bih, bhh, w2, pg2, w2pk);
  hipLaunchKernelGGL(lstm3_kernel, dim3(NBATCH), dim3(64), 0, stream,
                     pg2, Wih, Whh, bih, bhh, x3);
  hipLaunchKernelGGL(mlp_out_kernel, dim3(T_LEN), dim3(256), 0, stream,
                     x3, mfcc, w1, g1, be1, w2pk, g2, be2, w3, b3, WI, out);
}